// Round 1
// baseline (29823.639 us; speedup 1.0000x reference)
//
#include <hip/hip_runtime.h>
#include <hip/hip_bf16.h>

// ---------------------------------------------------------------------------
// PrimaryNetwork: hypernetwork-generated ResNet.
//   z_all (242,64) -> per-layer conv weights (36 layers) via 2-layer hypernet.
//   18 residual blocks; downsample at block 6 (16->32ch) and 12 (32->64ch).
//   BN scale folded into generated weights; BN shift + residual + ReLU folded
//   into conv epilogues; 1x1 stride-2 residual conv fused into conv2 of
//   downsample blocks. fp32 throughout (correctness baseline).
// ---------------------------------------------------------------------------

#define OFFS_LIST {0,1,2,3,4,5,6,7,8,9,10,11,12,14,18,22,26,30,34,38,42,46,50,54,58,66,82,98,114,130,146,162,178,194,210,226,242}
#define K_LIST    {1,1,1,1,1,1,1,1,1,1,1,1,1,2,2,2,2,2,2,2,2,2,2,2,2,4,4,4,4,4,4,4,4,4,4,4}
#define WOFF_LIST {0,2304,4608,6912,9216,11520,13824,16128,18432,20736,23040,25344,27648,32256,41472,50688,59904,69120,78336,87552,96768,105984,115200,124416,133632,152064,188928,225792,262656,299520,336384,373248,410112,446976,483840,520704}

__constant__ int d_offs[37] = OFFS_LIST;
__constant__ int d_k[36]    = K_LIST;
__constant__ int d_woff[36] = WOFF_LIST;

// --- BN prep: scale = g*rsqrt(v+eps), shift = b - m*scale  (37x64) ----------
__global__ void bn_prep(const float* __restrict__ g, const float* __restrict__ be,
                        const float* __restrict__ m, const float* __restrict__ v,
                        float* __restrict__ sc, float* __restrict__ sh) {
    int i = blockIdx.x * blockDim.x + threadIdx.x;
    if (i < 37 * 64) {
        float s = g[i] * rsqrtf(v[i] + 1e-5f);
        sc[i] = s;
        sh[i] = be[i] - m[i] * s;
    }
}

// --- Hypernetwork: one block per z-row (242). Writes BN-scale-folded weights.
__global__ void hyper_kernel(const float* __restrict__ z_all, const float* __restrict__ w2,
                             const float* __restrict__ b2, const float* __restrict__ w1,
                             const float* __restrict__ b1, const float* __restrict__ bnsc,
                             float* __restrict__ Wg) {
    int n = blockIdx.x;
    int tid = threadIdx.x;
    __shared__ float zrow[64];
    __shared__ float hin[1024];
    if (tid < 64) zrow[tid] = z_all[n * 64 + tid];
    __syncthreads();
    for (int mcol = tid; mcol < 1024; mcol += 256) {
        float acc = b2[mcol];
        #pragma unroll 8
        for (int d = 0; d < 64; ++d) acc += zrow[d] * w2[d * 1024 + mcol];
        hin[mcol] = acc;
    }
    __syncthreads();
    // locate layer L for this z-row
    int L = 0;
    while (n >= d_offs[L + 1]) ++L;
    int r = n - d_offs[L];
    int kk = d_k[L];
    int a = r / kk, b = r % kk;          // (out-group, in-group)
    int Cin = kk * 16;
    const float* scp = bnsc + (L + 1) * 64;
    float* wp = Wg + d_woff[L];
    for (int e = tid; e < 2304; e += 256) {
        int i = e / 144, o = e % 144;
        int j = o / 9, tap = o % 9;
        float acc = b1[o];
        #pragma unroll 8
        for (int d = 0; d < 64; ++d) acc += hin[i * 64 + d] * w1[d * 144 + o];
        acc *= scp[a * 16 + i];          // fold BN scale (per out-channel)
        wp[((a * 16 + i) * Cin + (b * 16 + j)) * 9 + tap] = acc;
    }
}

// --- First conv: 3->16, 32x32, +bias, BN row 0, ReLU ------------------------
__global__ void conv_first(const float* __restrict__ x, const float* __restrict__ w,
                           const float* __restrict__ cb, const float* __restrict__ g,
                           const float* __restrict__ be, const float* __restrict__ m,
                           const float* __restrict__ v, float* __restrict__ out) {
    int idx = blockIdx.x * 256 + threadIdx.x;   // total = 1024*16*32*32
    int px = idx & 31; int t = idx >> 5;
    int py = t & 31;   t >>= 5;
    int co = t & 15;   int b = t >> 4;
    const float* wp = w + co * 27;
    const float* ip = x + b * 3 * 1024;
    float acc = 0.f;
    #pragma unroll
    for (int ci = 0; ci < 3; ++ci) {
        #pragma unroll
        for (int ky = 0; ky < 3; ++ky) {
            int iy = py + ky - 1;
            if ((unsigned)iy < 32u) {
                #pragma unroll
                for (int kx = 0; kx < 3; ++kx) {
                    int ix = px + kx - 1;
                    if ((unsigned)ix < 32u)
                        acc += ip[ci * 1024 + iy * 32 + ix] * wp[ci * 9 + ky * 3 + kx];
                }
            }
        }
    }
    float s = g[co] * rsqrtf(v[co] + 1e-5f);
    float val = (acc + cb[co] - m[co]) * s + be[co];
    out[idx] = fmaxf(val, 0.f);
}

// --- Generic 3x3 conv, BN-scale pre-folded in w, epilogue adds shift --------
// mode 0: out = relu(conv + shift)
// mode 1: out = relu(conv + shift + res[idx])              (identity residual)
// mode 2: out = relu(conv + shift + 1x1s2(res; rw,rb))     (downsample block)
__global__ void conv_gen(const float* __restrict__ in, const float* __restrict__ w,
                         const float* __restrict__ sh, const float* __restrict__ res,
                         const float* __restrict__ rw, const float* __restrict__ rb,
                         float* __restrict__ out,
                         int Cin, int Hin, int Win, int Cout, int Hout, int Wout,
                         int stride, int mode, int resC, int total) {
    int idx = blockIdx.x * blockDim.x + threadIdx.x;
    if (idx >= total) return;
    int x = idx % Wout; int t = idx / Wout;
    int y = t % Hout;   t /= Hout;
    int co = t % Cout;  int b = t / Cout;
    const float* wp = w + co * Cin * 9;
    const float* ip = in + ((long)b * Cin) * Hin * Win;
    int y0 = y * stride - 1, x0 = x * stride - 1;
    float acc = 0.f;
    for (int ci = 0; ci < Cin; ++ci) {
        const float* ic = ip + ci * Hin * Win;
        const float* wc = wp + ci * 9;
        #pragma unroll
        for (int ky = 0; ky < 3; ++ky) {
            int iy = y0 + ky;
            if ((unsigned)iy < (unsigned)Hin) {
                #pragma unroll
                for (int kx = 0; kx < 3; ++kx) {
                    int ix = x0 + kx;
                    if ((unsigned)ix < (unsigned)Win)
                        acc += ic[iy * Win + ix] * wc[ky * 3 + kx];
                }
            }
        }
    }
    float val = acc + sh[co];
    if (mode == 1) {
        val += res[idx];
    } else if (mode == 2) {
        int rH = 2 * Hout, rW = 2 * Wout;
        float racc = rb[co];
        const float* rp = res + ((long)b * resC) * rH * rW;
        for (int ci = 0; ci < resC; ++ci)
            racc += rp[ci * rH * rW + (2 * y) * rW + (2 * x)] * rw[co * resC + ci];
        val += racc;
    }
    out[idx] = fmaxf(val, 0.f);
}

// --- avgpool (8x8) + FC (64->10) -------------------------------------------
__global__ void pool_fc(const float* __restrict__ X, const float* __restrict__ fw,
                        const float* __restrict__ fb, float* __restrict__ out) {
    int b = blockIdx.x;
    int c = threadIdx.x;            // 64 threads
    const float* p = X + ((long)b * 64 + c) * 64;
    float s = 0.f;
    #pragma unroll
    for (int i = 0; i < 64; ++i) s += p[i];
    __shared__ float pooled[64];
    pooled[c] = s * (1.f / 64.f);
    __syncthreads();
    if (c < 10) {
        float acc = fb[c];
        #pragma unroll
        for (int k = 0; k < 64; ++k) acc += pooled[k] * fw[c * 64 + k];
        out[b * 10 + c] = acc;
    }
}

extern "C" void kernel_launch(void* const* d_in, const int* in_sizes, int n_in,
                              void* d_out, int out_size, void* d_ws, size_t ws_size,
                              hipStream_t stream) {
    const float* x       = (const float*)d_in[0];
    const float* conv1_w = (const float*)d_in[1];
    const float* conv1_b = (const float*)d_in[2];
    const float* bn_g    = (const float*)d_in[3];
    const float* bn_b    = (const float*)d_in[4];
    const float* bn_m    = (const float*)d_in[5];
    const float* bn_v    = (const float*)d_in[6];
    const float* hn_w2   = (const float*)d_in[7];
    const float* hn_b2   = (const float*)d_in[8];
    const float* hn_w1   = (const float*)d_in[9];
    const float* hn_b1   = (const float*)d_in[10];
    const float* z_all   = (const float*)d_in[11];
    const float* res_w6  = (const float*)d_in[12];
    const float* res_b6  = (const float*)d_in[13];
    const float* res_w12 = (const float*)d_in[14];
    const float* res_b12 = (const float*)d_in[15];
    const float* fin_w   = (const float*)d_in[16];
    const float* fin_b   = (const float*)d_in[17];
    float* outp = (float*)d_out;

    float* wsf  = (float*)d_ws;
    float* Wg   = wsf;                  // 557568 generated-weight floats
    float* bnsc = wsf + 557568;         // 2368
    float* bnsh = wsf + 559936;         // 2368
    float* act0 = wsf + (1 << 20);
    float* act1 = act0 + (1 << 24);
    float* act2 = act1 + (1 << 24);     // total ~196 MiB

    static const int woff[36] = WOFF_LIST;

    bn_prep<<<10, 256, 0, stream>>>(bn_g, bn_b, bn_m, bn_v, bnsc, bnsh);
    hyper_kernel<<<242, 256, 0, stream>>>(z_all, hn_w2, hn_b2, hn_w1, hn_b1, bnsc, Wg);
    conv_first<<<65536, 256, 0, stream>>>(x, conv1_w, conv1_b, bn_g, bn_b, bn_m, bn_v, act0);

    float* X = act0; float* T1 = act1; float* T2 = act2;
    int H = 32, C = 16;
    for (int i = 0; i < 18; ++i) {
        int L1 = 2 * i, L2 = 2 * i + 1;
        bool down = (i == 6) || (i == 12);
        int stride = down ? 2 : 1;
        int Ho = down ? H / 2 : H;
        int Cout = down ? C * 2 : C;
        int tot = 1024 * Cout * Ho * Ho;
        int nb = (tot + 255) / 256;
        conv_gen<<<nb, 256, 0, stream>>>(X, Wg + woff[L1], bnsh + (L1 + 1) * 64,
                                         nullptr, nullptr, nullptr, T1,
                                         C, H, H, Cout, Ho, Ho, stride, 0, 0, tot);
        const float* rw = nullptr; const float* rb = nullptr;
        int mode = 1;
        if (down) { mode = 2; rw = (i == 6) ? res_w6 : res_w12; rb = (i == 6) ? res_b6 : res_b12; }
        conv_gen<<<nb, 256, 0, stream>>>(T1, Wg + woff[L2], bnsh + (L2 + 1) * 64,
                                         X, rw, rb, T2,
                                         Cout, Ho, Ho, Cout, Ho, Ho, 1, mode, C, tot);
        float* tmp = X; X = T2; T2 = tmp;
        C = Cout; H = Ho;
    }
    pool_fc<<<1024, 64, 0, stream>>>(X, fin_w, fin_b, outp);
}

// Round 2
// 8291.974 us; speedup vs baseline: 3.5967x; 3.5967x over previous
//
#include <hip/hip_runtime.h>
#include <hip/hip_bf16.h>

// ---------------------------------------------------------------------------
// Hypernetwork ResNet, fp32, NHWC, LDS-tiled implicit-GEMM conv.
//   - weights generated in [tap][ci][co] layout (BN scale folded) -> scalar
//     (SGPR) weight loads broadcast across the wave
//   - input tile staged in LDS as [cb][ry][rx][float4] (16B lane stride)
//   - each thread: 1 output pixel x Q output channels (Q=16..32 fp32 accs)
//   - BN shift + residual + ReLU + 1x1-s2 downsample residual fused in epilogue
// ---------------------------------------------------------------------------

#define OFFS_LIST {0,1,2,3,4,5,6,7,8,9,10,11,12,14,18,22,26,30,34,38,42,46,50,54,58,66,82,98,114,130,146,162,178,194,210,226,242}
#define K_LIST    {1,1,1,1,1,1,1,1,1,1,1,1,1,2,2,2,2,2,2,2,2,2,2,2,2,4,4,4,4,4,4,4,4,4,4,4}
#define H_LIST    {1,1,1,1,1,1,1,1,1,1,1,1,2,2,2,2,2,2,2,2,2,2,2,2,4,4,4,4,4,4,4,4,4,4,4,4}
#define WOFF_LIST {0,2304,4608,6912,9216,11520,13824,16128,18432,20736,23040,25344,27648,32256,41472,50688,59904,69120,78336,87552,96768,105984,115200,124416,133632,152064,188928,225792,262656,299520,336384,373248,410112,446976,483840,520704}

__constant__ int d_offs[37] = OFFS_LIST;
__constant__ int d_k[36]    = K_LIST;
__constant__ int d_hh[36]   = H_LIST;
__constant__ int d_woff[36] = WOFF_LIST;

// --- prep: BN scale/shift + transpose 1x1 residual conv weights -------------
__global__ void prep(const float* __restrict__ g, const float* __restrict__ be,
                     const float* __restrict__ m, const float* __restrict__ v,
                     const float* __restrict__ rw6, const float* __restrict__ rw12,
                     float* __restrict__ sc, float* __restrict__ sh,
                     float* __restrict__ rwT6, float* __restrict__ rwT12) {
    int i = blockIdx.x * blockDim.x + threadIdx.x;
    if (i < 2368) {
        float s = g[i] * rsqrtf(v[i] + 1e-5f);
        sc[i] = s;
        sh[i] = be[i] - m[i] * s;
    } else if (i < 2368 + 512) {
        int t = i - 2368;              // rw6: (32,16) -> rwT6[ci*32+co]
        int co = t % 32, ci = t / 32;
        rwT6[ci * 32 + co] = rw6[co * 16 + ci];
    } else if (i < 2368 + 512 + 2048) {
        int t = i - 2368 - 512;        // rw12: (64,32) -> rwT12[ci*64+co]
        int co = t % 64, ci = t / 64;
        rwT12[ci * 64 + co] = rw12[co * 32 + ci];
    }
}

// --- Hypernetwork: one block per z-row. Emits weights as [tap][ci][co]. -----
__global__ void hyper_kernel(const float* __restrict__ z_all, const float* __restrict__ w2,
                             const float* __restrict__ b2, const float* __restrict__ w1,
                             const float* __restrict__ b1, const float* __restrict__ bnsc,
                             float* __restrict__ Wg) {
    int n = blockIdx.x;
    int tid = threadIdx.x;
    __shared__ float zrow[64];
    __shared__ float hin[1024];
    if (tid < 64) zrow[tid] = z_all[n * 64 + tid];
    __syncthreads();
    for (int mcol = tid; mcol < 1024; mcol += 256) {
        float acc = b2[mcol];
        #pragma unroll 8
        for (int d = 0; d < 64; ++d) acc += zrow[d] * w2[d * 1024 + mcol];
        hin[mcol] = acc;
    }
    __syncthreads();
    int L = 0;
    while (n >= d_offs[L + 1]) ++L;
    int r = n - d_offs[L];
    int kk = d_k[L];
    int a = r / kk, bb = r % kk;         // (out-group, in-group)
    int Cin = kk * 16;
    int Cout = d_hh[L] * 16;
    const float* scp = bnsc + (L + 1) * 64;
    float* wp = Wg + d_woff[L];
    for (int e = tid; e < 2304; e += 256) {
        int i = e / 144, o = e % 144;
        int j = o / 9, tap = o % 9;
        float acc = b1[o];
        #pragma unroll 8
        for (int d = 0; d < 64; ++d) acc += hin[i * 64 + d] * w1[d * 144 + o];
        int co = a * 16 + i;
        acc *= scp[co];                  // fold BN scale
        wp[(tap * Cin + (bb * 16 + j)) * Cout + co] = acc;
    }
}

// --- First conv: 3->16, NCHW in -> NHWC out, +bias, BN row 0, ReLU ----------
__global__ void conv_first(const float* __restrict__ x, const float* __restrict__ cw,
                           const float* __restrict__ cb, const float* __restrict__ g,
                           const float* __restrict__ be, const float* __restrict__ m,
                           const float* __restrict__ v, float* __restrict__ out) {
    int idx = blockIdx.x * 256 + threadIdx.x;   // (b, y, x): 1024*32*32
    int px = idx & 31; int t = idx >> 5;
    int py = t & 31;   int b = t >> 5;
    float acc[16];
    #pragma unroll
    for (int co = 0; co < 16; ++co) acc[co] = 0.f;
    const float* ip = x + (long)b * 3 * 1024;
    #pragma unroll 1
    for (int ci = 0; ci < 3; ++ci) {
        #pragma unroll 1
        for (int ky = 0; ky < 3; ++ky) {
            int iy = py + ky - 1;
            if ((unsigned)iy >= 32u) continue;
            #pragma unroll
            for (int kx = 0; kx < 3; ++kx) {
                int ix = px + kx - 1;
                if ((unsigned)ix < 32u) {
                    float xv = ip[ci * 1024 + iy * 32 + ix];
                    #pragma unroll
                    for (int co = 0; co < 16; ++co)
                        acc[co] += xv * cw[co * 27 + ci * 9 + ky * 3 + kx];
                }
            }
        }
    }
    long o = ((long)(b * 32 + py) * 32 + px) * 16;
    #pragma unroll
    for (int co = 0; co < 16; ++co) {
        float s = g[co] * rsqrtf(v[co] + 1e-5f);
        float val = (acc[co] + cb[co] - m[co]) * s + be[co];
        out[o + co] = fmaxf(val, 0.f);
    }
}

// --- Tiled conv 3x3, NHWC, weights [tap][ci][co] (BN scale folded) ----------
// mode 0: relu(conv + sh) | 1: relu(conv + sh + res) | 2: relu(conv + sh + 1x1s2(res))
template<int CIN, int COUT, int HIN, int STRIDE, int TH, int TW, int CG>
__global__ __launch_bounds__(256) void conv_tile(
        const float* __restrict__ in, const float* __restrict__ w,
        const float* __restrict__ shp, const float* __restrict__ res,
        const float* __restrict__ rwT, const float* __restrict__ rb,
        float* __restrict__ out, int mode, int CR, int HR) {
    constexpr int HOUT = HIN / STRIDE;
    constexpr int CB = CIN / 4;
    constexpr int Q = COUT / CG;
    constexpr int IH = (TH - 1) * STRIDE + 3;
    constexpr int IW = (TW - 1) * STRIDE + 3;
    constexpr int TILES_Y = HOUT / TH, TILES_X = HOUT / TW;
    __shared__ float4 lds[CB * IH * IW];

    int tid = threadIdx.x;
    int bid = blockIdx.x;
    int tile = bid % (TILES_Y * TILES_X);
    int b = bid / (TILES_Y * TILES_X);
    int ty = tile / TILES_X, tx = tile % TILES_X;
    int Y0 = ty * TH, X0 = tx * TW;

    // ---- stage input tile (zero-padded halo) ----
    int gy0 = Y0 * STRIDE - 1, gx0 = X0 * STRIDE - 1;
    constexpr int SLOTS = CB * IH * IW;
    for (int s = tid; s < SLOTS; s += 256) {
        int cb = s % CB; int t = s / CB;
        int rx = t % IW; int ry = t / IW;
        int gy = gy0 + ry, gx = gx0 + rx;
        float4 val = make_float4(0.f, 0.f, 0.f, 0.f);
        if ((unsigned)gy < (unsigned)HIN && (unsigned)gx < (unsigned)HIN)
            val = *(const float4*)(in + ((long)(b * HIN + gy) * HIN + gx) * CIN + cb * 4);
        lds[cb * IH * IW + t] = val;
    }
    __syncthreads();

    // ---- compute ----
    int x = tid % TW;
    int y = (tid / TW) % TH;
    int cg = tid / (TH * TW);                       // wave-uniform by construction
    int cob = __builtin_amdgcn_readfirstlane(cg * Q);
    float acc[Q];
    #pragma unroll
    for (int q = 0; q < Q; ++q) acc[q] = 0.f;
    int pbase = (y * STRIDE) * IW + x * STRIDE;

    #pragma unroll 1
    for (int tap = 0; tap < 9; ++tap) {
        int ky = tap / 3, kx = tap % 3;
        int pidx = pbase + ky * IW + kx;
        const float* wp = w + (tap * CIN) * COUT + cob;
        #pragma unroll
        for (int cb = 0; cb < CB; ++cb) {
            float4 a = lds[cb * IH * IW + pidx];
            const float* wq = wp + (cb * 4) * COUT;
            #pragma unroll
            for (int q = 0; q < Q; ++q)
                acc[q] += a.x * wq[q] + a.y * wq[COUT + q]
                        + a.z * wq[2 * COUT + q] + a.w * wq[3 * COUT + q];
        }
    }

    // ---- epilogue ----
    long oidx = ((long)(b * HOUT + Y0 + y) * HOUT + (X0 + x)) * COUT + cob;
    float vq[Q];
    #pragma unroll
    for (int q = 0; q < Q; ++q) vq[q] = acc[q] + shp[cob + q];
    if (mode == 1) {
        #pragma unroll
        for (int q = 0; q < Q; q += 4) {
            float4 r = *(const float4*)(res + oidx + q);
            vq[q] += r.x; vq[q+1] += r.y; vq[q+2] += r.z; vq[q+3] += r.w;
        }
    } else if (mode == 2) {
        int ry2 = (Y0 + y) * 2, rx2 = (X0 + x) * 2;
        #pragma unroll 1
        for (int cb = 0; cb < CR / 4; ++cb) {
            float4 r = *(const float4*)(res + ((long)(b * HR + ry2) * HR + rx2) * CR + cb * 4);
            const float* rt = rwT + (cb * 4) * COUT + cob;
            #pragma unroll
            for (int q = 0; q < Q; ++q)
                vq[q] += r.x * rt[q] + r.y * rt[COUT + q]
                       + r.z * rt[2 * COUT + q] + r.w * rt[3 * COUT + q];
        }
        #pragma unroll
        for (int q = 0; q < Q; ++q) vq[q] += rb[cob + q];
    }
    #pragma unroll
    for (int q = 0; q < Q; q += 4) {
        float4 o = make_float4(fmaxf(vq[q], 0.f),   fmaxf(vq[q+1], 0.f),
                               fmaxf(vq[q+2], 0.f), fmaxf(vq[q+3], 0.f));
        *(float4*)(out + oidx + q) = o;
    }
}

// --- avgpool (8x8, NHWC) + FC (64->10) --------------------------------------
__global__ void pool_fc(const float* __restrict__ X, const float* __restrict__ fw,
                        const float* __restrict__ fb, float* __restrict__ out) {
    int b = blockIdx.x;
    int c = threadIdx.x;            // 64 threads
    float s = 0.f;
    #pragma unroll
    for (int p = 0; p < 64; ++p) s += X[((long)b * 64 + p) * 64 + c];
    __shared__ float pooled[64];
    pooled[c] = s * (1.f / 64.f);
    __syncthreads();
    if (c < 10) {
        float acc = fb[c];
        #pragma unroll
        for (int k = 0; k < 64; ++k) acc += pooled[k] * fw[c * 64 + k];
        out[b * 10 + c] = acc;
    }
}

extern "C" void kernel_launch(void* const* d_in, const int* in_sizes, int n_in,
                              void* d_out, int out_size, void* d_ws, size_t ws_size,
                              hipStream_t stream) {
    const float* x       = (const float*)d_in[0];
    const float* conv1_w = (const float*)d_in[1];
    const float* conv1_b = (const float*)d_in[2];
    const float* bn_g    = (const float*)d_in[3];
    const float* bn_b    = (const float*)d_in[4];
    const float* bn_m    = (const float*)d_in[5];
    const float* bn_v    = (const float*)d_in[6];
    const float* hn_w2   = (const float*)d_in[7];
    const float* hn_b2   = (const float*)d_in[8];
    const float* hn_w1   = (const float*)d_in[9];
    const float* hn_b1   = (const float*)d_in[10];
    const float* z_all   = (const float*)d_in[11];
    const float* res_w6  = (const float*)d_in[12];
    const float* res_b6  = (const float*)d_in[13];
    const float* res_w12 = (const float*)d_in[14];
    const float* res_b12 = (const float*)d_in[15];
    const float* fin_w   = (const float*)d_in[16];
    const float* fin_b   = (const float*)d_in[17];
    float* outp = (float*)d_out;

    float* wsf   = (float*)d_ws;
    float* Wg    = wsf;                   // 557568
    float* bnsc  = wsf + 557568;          // 2368
    float* bnsh  = wsf + 559936;          // 2368
    float* rwT6  = wsf + 562304;          // 512
    float* rwT12 = wsf + 562816;          // 2048
    float* act0  = wsf + (1 << 20);
    float* act1  = act0 + (1 << 24);
    float* act2  = act1 + (1 << 24);

    static const int woff[36] = WOFF_LIST;

    prep<<<20, 256, 0, stream>>>(bn_g, bn_b, bn_m, bn_v, res_w6, res_w12,
                                 bnsc, bnsh, rwT6, rwT12);
    hyper_kernel<<<242, 256, 0, stream>>>(z_all, hn_w2, hn_b2, hn_w1, hn_b1, bnsc, Wg);
    conv_first<<<4096, 256, 0, stream>>>(x, conv1_w, conv1_b, bn_g, bn_b, bn_m, bn_v, act0);

    float* X = act0; float* T1 = act1; float* T2 = act2;
    for (int i = 0; i < 18; ++i) {
        int L1 = 2 * i, L2 = 2 * i + 1;
        const float* w1p = Wg + woff[L1];
        const float* w2p = Wg + woff[L2];
        const float* s1p = bnsh + (L1 + 1) * 64;
        const float* s2p = bnsh + (L2 + 1) * 64;
        if (i < 6) {
            conv_tile<16,16,32,1,16,16,1><<<4096, 256, 0, stream>>>(
                X, w1p, s1p, nullptr, nullptr, nullptr, T1, 0, 0, 0);
            conv_tile<16,16,32,1,16,16,1><<<4096, 256, 0, stream>>>(
                T1, w2p, s2p, X, nullptr, nullptr, T2, 1, 0, 0);
        } else if (i == 6) {
            conv_tile<16,32,32,2,8,16,2><<<2048, 256, 0, stream>>>(
                X, w1p, s1p, nullptr, nullptr, nullptr, T1, 0, 0, 0);
            conv_tile<32,32,16,1,16,16,1><<<1024, 256, 0, stream>>>(
                T1, w2p, s2p, X, rwT6, res_b6, T2, 2, 16, 32);
        } else if (i < 12) {
            conv_tile<32,32,16,1,16,16,1><<<1024, 256, 0, stream>>>(
                X, w1p, s1p, nullptr, nullptr, nullptr, T1, 0, 0, 0);
            conv_tile<32,32,16,1,16,16,1><<<1024, 256, 0, stream>>>(
                T1, w2p, s2p, X, nullptr, nullptr, T2, 1, 0, 0);
        } else if (i == 12) {
            conv_tile<32,64,16,2,8,8,4><<<1024, 256, 0, stream>>>(
                X, w1p, s1p, nullptr, nullptr, nullptr, T1, 0, 0, 0);
            conv_tile<64,64,8,1,8,8,4><<<1024, 256, 0, stream>>>(
                T1, w2p, s2p, X, rwT12, res_b12, T2, 2, 32, 16);
        } else {
            conv_tile<64,64,8,1,8,8,4><<<1024, 256, 0, stream>>>(
                X, w1p, s1p, nullptr, nullptr, nullptr, T1, 0, 0, 0);
            conv_tile<64,64,8,1,8,8,4><<<1024, 256, 0, stream>>>(
                T1, w2p, s2p, X, nullptr, nullptr, T2, 1, 0, 0);
        }
        float* tmp = X; X = T2; T2 = tmp;
    }
    pool_fc<<<1024, 64, 0, stream>>>(X, fin_w, fin_b, outp);
}

// Round 3
// 1354.500 us; speedup vs baseline: 22.0182x; 6.1218x over previous
//
#include <hip/hip_runtime.h>
#include <hip/hip_bf16.h>

// ---------------------------------------------------------------------------
// Hypernetwork ResNet. bf16x3-split MFMA implicit-GEMM conv (fp32-equivalent
// precision): every fp32 value x = x1+x2+x3 (3 bf16 terms); products kept:
// x1w1, x1w2+x2w1, x1w3+x2w2+x3w1 (6 MFMA per logical fp32 MFMA), fp32 accum.
//   - activations fp32 NHWC in global; split to 3 bf16 LDS planes at staging
//   - weights pre-split + fragment-ordered by split_w (one dwordx4/lane/k-step)
//   - A/B fragments use the SAME (lane-group, j)->k map, so any HW k-perm ok
//   - K-loop barrier-free (tile staged once); epilogue fuses BN shift,
//     residual (identity or 1x1-s2), ReLU
// ---------------------------------------------------------------------------

typedef __attribute__((ext_vector_type(8))) short bf16x8;
typedef __attribute__((ext_vector_type(4))) float f32x4;
typedef unsigned short ushort_t;

#define OFFS_LIST {0,1,2,3,4,5,6,7,8,9,10,11,12,14,18,22,26,30,34,38,42,46,50,54,58,66,82,98,114,130,146,162,178,194,210,226,242}
#define K_LIST    {1,1,1,1,1,1,1,1,1,1,1,1,1,2,2,2,2,2,2,2,2,2,2,2,2,4,4,4,4,4,4,4,4,4,4,4}
#define H_LIST    {1,1,1,1,1,1,1,1,1,1,1,1,2,2,2,2,2,2,2,2,2,2,2,2,4,4,4,4,4,4,4,4,4,4,4,4}
#define WOFF_LIST {0,2304,4608,6912,9216,11520,13824,16128,18432,20736,23040,25344,27648,32256,41472,50688,59904,69120,78336,87552,96768,105984,115200,124416,133632,152064,188928,225792,262656,299520,336384,373248,410112,446976,483840,520704}
#define CIN_LIST  {16,16,16,16,16,16,16,16,16,16,16,16,16,32,32,32,32,32,32,32,32,32,32,32,32,64,64,64,64,64,64,64,64,64,64,64}
#define COUT_LIST {16,16,16,16,16,16,16,16,16,16,16,16,32,32,32,32,32,32,32,32,32,32,32,32,64,64,64,64,64,64,64,64,64,64,64,64}
#define WFOFF_LIST {0,7680,15360,23040,30720,38400,46080,53760,61440,69120,76800,84480,92160,107520,135168,162816,190464,218112,245760,273408,301056,328704,356352,384000,411648,466944,577536,688128,798720,909312,1019904,1130496,1241088,1351680,1462272,1572864}

__constant__ int d_offs[37]  = OFFS_LIST;
__constant__ int d_k[36]     = K_LIST;
__constant__ int d_hh[36]    = H_LIST;
__constant__ int d_woff[36]  = WOFF_LIST;
__constant__ int d_cin[36]   = CIN_LIST;
__constant__ int d_cout[36]  = COUT_LIST;
__constant__ int d_wfoff[36] = WFOFF_LIST;

// 3-way bf16 split, round-to-nearest-ish via +0x8000 carry. Residual <= 2^-24.
__device__ inline void split3(float x, ushort_t& h, ushort_t& m, ushort_t& l) {
    unsigned xb = __float_as_uint(x);
    unsigned hb = (xb + 0x8000u) >> 16;
    float fh = __uint_as_float(hb << 16);
    float r = x - fh;
    unsigned rb2 = __float_as_uint(r);
    unsigned mb = (rb2 + 0x8000u) >> 16;
    float fm = __uint_as_float(mb << 16);
    float r2 = r - fm;
    unsigned lb = (__float_as_uint(r2) + 0x8000u) >> 16;
    h = (ushort_t)hb; m = (ushort_t)mb; l = (ushort_t)lb;
}

// --- prep: BN scale/shift + transpose 1x1 residual conv weights -------------
__global__ void prep(const float* __restrict__ g, const float* __restrict__ be,
                     const float* __restrict__ m, const float* __restrict__ v,
                     const float* __restrict__ rw6, const float* __restrict__ rw12,
                     float* __restrict__ sc, float* __restrict__ sh,
                     float* __restrict__ rwT6, float* __restrict__ rwT12) {
    int i = blockIdx.x * blockDim.x + threadIdx.x;
    if (i < 2368) {
        float s = g[i] * rsqrtf(v[i] + 1e-5f);
        sc[i] = s;
        sh[i] = be[i] - m[i] * s;
    } else if (i < 2368 + 512) {
        int t = i - 2368;
        int co = t % 32, ci = t / 32;
        rwT6[ci * 32 + co] = rw6[co * 16 + ci];
    } else if (i < 2368 + 512 + 2048) {
        int t = i - 2368 - 512;
        int co = t % 64, ci = t / 64;
        rwT12[ci * 64 + co] = rw12[co * 32 + ci];
    }
}

// --- Hypernetwork: one block per z-row. Emits fp32 weights [k][co]. ---------
__global__ void hyper_kernel(const float* __restrict__ z_all, const float* __restrict__ w2,
                             const float* __restrict__ b2, const float* __restrict__ w1,
                             const float* __restrict__ b1, const float* __restrict__ bnsc,
                             float* __restrict__ Wg) {
    int n = blockIdx.x;
    int tid = threadIdx.x;
    __shared__ float zrow[64];
    __shared__ float hin[1024];
    if (tid < 64) zrow[tid] = z_all[n * 64 + tid];
    __syncthreads();
    for (int mcol = tid; mcol < 1024; mcol += 256) {
        float acc = b2[mcol];
        #pragma unroll 8
        for (int d = 0; d < 64; ++d) acc += zrow[d] * w2[d * 1024 + mcol];
        hin[mcol] = acc;
    }
    __syncthreads();
    int L = 0;
    while (n >= d_offs[L + 1]) ++L;
    int r = n - d_offs[L];
    int kk = d_k[L];
    int a = r / kk, bb = r % kk;
    int Cin = kk * 16;
    int Cout = d_hh[L] * 16;
    const float* scp = bnsc + (L + 1) * 64;
    float* wp = Wg + d_woff[L];
    for (int e = tid; e < 2304; e += 256) {
        int i = e / 144, o = e % 144;
        int j = o / 9, tap = o % 9;
        float acc = b1[o];
        #pragma unroll 8
        for (int d = 0; d < 64; ++d) acc += hin[i * 64 + d] * w1[d * 144 + o];
        int co = a * 16 + i;
        acc *= scp[co];
        wp[(tap * Cin + (bb * 16 + j)) * Cout + co] = acc;
    }
}

// --- split weights into bf16x3 fragment-ordered blocks ----------------------
// Layout per layer: [ks][nt][plane][lane(64)][j(8)] ushort; zero beyond K.
__global__ void split_w(const float* __restrict__ Wg, ushort_t* __restrict__ Wf) {
    int L = blockIdx.y;
    int CIN = d_cin[L], COUT = d_cout[L];
    int K = 9 * CIN, NKS = (K + 31) / 32, NT = COUT / 16;
    int total = NKS * NT * 512;
    int idx = blockIdx.x * 256 + threadIdx.x;
    if (idx >= total) return;
    int j = idx & 7, lane = (idx >> 3) & 63, t = idx >> 9;
    int nt = t % NT, ks = t / NT;
    int gg = lane >> 4, r16 = lane & 15;
    int k = ks * 32 + gg * 8 + j, co = nt * 16 + r16;
    float wv = (k < K) ? Wg[d_woff[L] + k * COUT + co] : 0.f;
    ushort_t h, m, l;
    split3(wv, h, m, l);
    int base = d_wfoff[L] + ((ks * NT + nt) * 3) * 512 + lane * 8 + j;
    Wf[base] = h; Wf[base + 512] = m; Wf[base + 1024] = l;
}

// --- First conv: 3->16, NCHW in -> NHWC fp32 out, +bias, BN row 0, ReLU -----
__global__ void conv_first(const float* __restrict__ x, const float* __restrict__ cw,
                           const float* __restrict__ cb, const float* __restrict__ g,
                           const float* __restrict__ be, const float* __restrict__ m,
                           const float* __restrict__ v, float* __restrict__ out) {
    int idx = blockIdx.x * 256 + threadIdx.x;
    int px = idx & 31; int t = idx >> 5;
    int py = t & 31;   int b = t >> 5;
    float acc[16];
    #pragma unroll
    for (int co = 0; co < 16; ++co) acc[co] = 0.f;
    const float* ip = x + (long)b * 3 * 1024;
    #pragma unroll 1
    for (int ci = 0; ci < 3; ++ci) {
        #pragma unroll 1
        for (int ky = 0; ky < 3; ++ky) {
            int iy = py + ky - 1;
            if ((unsigned)iy >= 32u) continue;
            #pragma unroll
            for (int kx = 0; kx < 3; ++kx) {
                int ix = px + kx - 1;
                if ((unsigned)ix < 32u) {
                    float xv = ip[ci * 1024 + iy * 32 + ix];
                    #pragma unroll
                    for (int co = 0; co < 16; ++co)
                        acc[co] += xv * cw[co * 27 + ci * 9 + ky * 3 + kx];
                }
            }
        }
    }
    long o = ((long)(b * 32 + py) * 32 + px) * 16;
    #pragma unroll
    for (int co = 0; co < 16; ++co) {
        float s = g[co] * rsqrtf(v[co] + 1e-5f);
        float val = (acc[co] + cb[co] - m[co]) * s + be[co];
        out[o + co] = fmaxf(val, 0.f);
    }
}

// --- MFMA conv 3x3 (bf16x3), NHWC fp32 in/out -------------------------------
template<int CIN, int COUT, int HIN, int STRIDE, int TH, int TW, int MODE, int CR, int HR>
__global__ __launch_bounds__(256) void conv_mfma(
        const float* __restrict__ in, const ushort_t* __restrict__ wf,
        const float* __restrict__ shp, const float* __restrict__ res,
        const float* __restrict__ rwT, const float* __restrict__ rb,
        float* __restrict__ out) {
    constexpr int HOUT = HIN / STRIDE;
    constexpr int CG8 = CIN / 8;
    constexpr int IH = (TH - 1) * STRIDE + 3;
    constexpr int IW = (TW - 1) * STRIDE + 3;
    constexpr int K = 9 * CIN;
    constexpr int NKS = (K + 31) / 32;
    constexpr bool TAIL = (K % 32) != 0;
    constexpr int NT = COUT / 16;
    constexpr int NMT = TH * TW / 16;
    constexpr int MTW = NMT / 4;
    constexpr int PADC = ((2 - (IH * IW)) % 8 + 8) % 8;   // c-group bank stagger
    constexpr int CSTU = IH * IW + PADC;                  // 16B units per c-plane
    constexpr int PST = CG8 * CSTU;                       // 16B units per bf16 plane
    constexpr int TX = HOUT / TW, TY = HOUT / TH;

    __shared__ uint4 lds[3 * PST];

    int tid = threadIdx.x;
    int bid = blockIdx.x;
    int tile = bid % (TY * TX);
    int b = bid / (TY * TX);
    int ty = tile / TX, tx = tile % TX;
    int Y0 = ty * TH, X0 = tx * TW;
    int gy0 = Y0 * STRIDE - 1, gx0 = X0 * STRIDE - 1;

    // ---- stage: fp32 NHWC global -> 3 bf16 planes in LDS (zero halo) ----
    for (int e = tid; e < CG8 * IH * IW; e += 256) {
        int c8 = e / (IH * IW); int rr = e % (IH * IW);
        int ly = rr / IW, lx = rr % IW;
        int gy = gy0 + ly, gx = gx0 + lx;
        float vv[8];
        if ((unsigned)gy < (unsigned)HIN && (unsigned)gx < (unsigned)HIN) {
            const float4* p = (const float4*)(in + ((long)(b * HIN + gy) * HIN + gx) * CIN + c8 * 8);
            float4 a0 = p[0], a1 = p[1];
            vv[0]=a0.x; vv[1]=a0.y; vv[2]=a0.z; vv[3]=a0.w;
            vv[4]=a1.x; vv[5]=a1.y; vv[6]=a1.z; vv[7]=a1.w;
        } else {
            #pragma unroll
            for (int q = 0; q < 8; ++q) vv[q] = 0.f;
        }
        union { ushort_t u[8]; uint4 q4; } H, M, L;
        #pragma unroll
        for (int q = 0; q < 8; ++q) split3(vv[q], H.u[q], M.u[q], L.u[q]);
        int a16 = c8 * CSTU + rr;
        lds[a16] = H.q4; lds[PST + a16] = M.q4; lds[2 * PST + a16] = L.q4;
    }
    __syncthreads();

    int lane = tid & 63, wid = tid >> 6;
    int g = lane >> 4, r16 = lane & 15;

    f32x4 acc[MTW][NT] = {};

    int pbase[MTW];
    #pragma unroll
    for (int mt = 0; mt < MTW; ++mt) {
        int pid = (wid + 4 * mt) * 16 + r16;
        int py = pid / TW, px = pid % TW;
        pbase[mt] = (py * STRIDE) * IW + px * STRIDE;
    }

    #pragma unroll
    for (int ks = 0; ks < NKS; ++ks) {
        // B fragments (global, L1-broadcast across waves/blocks)
        bf16x8 bfr[NT][3];
        #pragma unroll
        for (int nt = 0; nt < NT; ++nt)
            #pragma unroll
            for (int p = 0; p < 3; ++p)
                bfr[nt][p] = *(const bf16x8*)(wf + ((ks * NT + nt) * 3 + p) * 512 + lane * 8);

        // A offset for this k-step: k = ks*32 + g*8 + j -> (tap, ci-octet)
        int k0 = ks * 32 + g * 8;
        int tap = k0 / CIN;
        int ci8 = (k0 % CIN) >> 3;
        int ky = (tap * 11) >> 5;
        int kx = tap - 3 * ky;
        int ofs = ci8 * CSTU + ky * IW + kx;

        #pragma unroll
        for (int mt = 0; mt < MTW; ++mt) {
            int e16 = ofs + pbase[mt];
            if (TAIL && ks == NKS - 1) e16 = (g < 2) ? e16 : 0;  // B is zero there
            const uint4* ap = lds + e16;
            bf16x8 ah = *(const bf16x8*)(ap);
            bf16x8 am = *(const bf16x8*)(ap + PST);
            bf16x8 al = *(const bf16x8*)(ap + 2 * PST);
            #pragma unroll
            for (int nt = 0; nt < NT; ++nt) {
                f32x4 c = acc[mt][nt];
                c = __builtin_amdgcn_mfma_f32_16x16x32_bf16(ah, bfr[nt][0], c, 0, 0, 0);
                c = __builtin_amdgcn_mfma_f32_16x16x32_bf16(ah, bfr[nt][1], c, 0, 0, 0);
                c = __builtin_amdgcn_mfma_f32_16x16x32_bf16(am, bfr[nt][0], c, 0, 0, 0);
                c = __builtin_amdgcn_mfma_f32_16x16x32_bf16(ah, bfr[nt][2], c, 0, 0, 0);
                c = __builtin_amdgcn_mfma_f32_16x16x32_bf16(am, bfr[nt][1], c, 0, 0, 0);
                c = __builtin_amdgcn_mfma_f32_16x16x32_bf16(al, bfr[nt][0], c, 0, 0, 0);
                acc[mt][nt] = c;
            }
        }
    }

    // ---- epilogue: C-frag (col=lane&15 -> cout, row=(lane>>4)*4+reg -> pixel)
    #pragma unroll
    for (int mt = 0; mt < MTW; ++mt) {
        #pragma unroll
        for (int nt = 0; nt < NT; ++nt) {
            int co = nt * 16 + r16;
            float shv = shp[co];
            #pragma unroll
            for (int reg = 0; reg < 4; ++reg) {
                int pid = (wid + 4 * mt) * 16 + g * 4 + reg;
                int py = pid / TW, px = pid % TW;
                int gy = Y0 + py, gx = X0 + px;
                long oidx = ((long)(b * HOUT + gy) * HOUT + gx) * COUT + co;
                float val = acc[mt][nt][reg] + shv;
                if (MODE == 1) val += res[oidx];
                if (MODE == 2) {
                    float racc = rb[co];
                    const float* rp = res + ((long)(b * HR + 2 * gy) * HR + 2 * gx) * CR;
                    #pragma unroll 4
                    for (int ci = 0; ci < CR; ++ci) racc += rp[ci] * rwT[ci * COUT + co];
                    val += racc;
                }
                out[oidx] = fmaxf(val, 0.f);
            }
        }
    }
}

// --- avgpool (8x8, NHWC) + FC (64->10) --------------------------------------
__global__ void pool_fc(const float* __restrict__ X, const float* __restrict__ fw,
                        const float* __restrict__ fb, float* __restrict__ out) {
    int b = blockIdx.x;
    int c = threadIdx.x;
    float s = 0.f;
    #pragma unroll
    for (int p = 0; p < 64; ++p) s += X[((long)b * 64 + p) * 64 + c];
    __shared__ float pooled[64];
    pooled[c] = s * (1.f / 64.f);
    __syncthreads();
    if (c < 10) {
        float acc = fb[c];
        #pragma unroll
        for (int k = 0; k < 64; ++k) acc += pooled[k] * fw[c * 64 + k];
        out[b * 10 + c] = acc;
    }
}

extern "C" void kernel_launch(void* const* d_in, const int* in_sizes, int n_in,
                              void* d_out, int out_size, void* d_ws, size_t ws_size,
                              hipStream_t stream) {
    const float* x       = (const float*)d_in[0];
    const float* conv1_w = (const float*)d_in[1];
    const float* conv1_b = (const float*)d_in[2];
    const float* bn_g    = (const float*)d_in[3];
    const float* bn_b    = (const float*)d_in[4];
    const float* bn_m    = (const float*)d_in[5];
    const float* bn_v    = (const float*)d_in[6];
    const float* hn_w2   = (const float*)d_in[7];
    const float* hn_b2   = (const float*)d_in[8];
    const float* hn_w1   = (const float*)d_in[9];
    const float* hn_b1   = (const float*)d_in[10];
    const float* z_all   = (const float*)d_in[11];
    const float* res_w6  = (const float*)d_in[12];
    const float* res_b6  = (const float*)d_in[13];
    const float* res_w12 = (const float*)d_in[14];
    const float* res_b12 = (const float*)d_in[15];
    const float* fin_w   = (const float*)d_in[16];
    const float* fin_b   = (const float*)d_in[17];
    float* outp = (float*)d_out;

    float* wsf      = (float*)d_ws;
    float* Wg       = wsf;                   // 557568 fp32
    float* bnsc     = wsf + 557568;          // 2368
    float* bnsh     = wsf + 559936;          // 2368
    float* rwT6     = wsf + 562304;          // 512
    float* rwT12    = wsf + 562816;          // 2048
    ushort_t* Wfrag = (ushort_t*)(wsf + 564864);  // 1683456 ushorts
    float* act0     = wsf + (1 << 21);
    float* act1     = act0 + (1 << 24);
    float* act2     = act1 + (1 << 24);

    static const int woff[36]  = WOFF_LIST;
    static const int wfoff[36] = WFOFF_LIST;
    (void)woff;

    prep<<<20, 256, 0, stream>>>(bn_g, bn_b, bn_m, bn_v, res_w6, res_w12,
                                 bnsc, bnsh, rwT6, rwT12);
    hyper_kernel<<<242, 256, 0, stream>>>(z_all, hn_w2, hn_b2, hn_w1, hn_b1, bnsc, Wg);
    split_w<<<dim3(144, 36), 256, 0, stream>>>(Wg, Wfrag);
    conv_first<<<4096, 256, 0, stream>>>(x, conv1_w, conv1_b, bn_g, bn_b, bn_m, bn_v, act0);

    float* X = act0; float* T1 = act1; float* T2 = act2;
    for (int i = 0; i < 18; ++i) {
        int L1 = 2 * i, L2 = 2 * i + 1;
        const ushort_t* w1p = Wfrag + wfoff[L1];
        const ushort_t* w2p = Wfrag + wfoff[L2];
        const float* s1p = bnsh + (L1 + 1) * 64;
        const float* s2p = bnsh + (L2 + 1) * 64;
        if (i < 6) {
            conv_mfma<16,16,32,1,16,16,0,1,1><<<4096, 256, 0, stream>>>(
                X, w1p, s1p, nullptr, nullptr, nullptr, T1);
            conv_mfma<16,16,32,1,16,16,1,1,1><<<4096, 256, 0, stream>>>(
                T1, w2p, s2p, X, nullptr, nullptr, T2);
        } else if (i == 6) {
            conv_mfma<16,32,32,2,8,16,0,1,1><<<2048, 256, 0, stream>>>(
                X, w1p, s1p, nullptr, nullptr, nullptr, T1);
            conv_mfma<32,32,16,1,8,16,2,16,32><<<2048, 256, 0, stream>>>(
                T1, w2p, s2p, X, rwT6, res_b6, T2);
        } else if (i < 12) {
            conv_mfma<32,32,16,1,8,16,0,1,1><<<2048, 256, 0, stream>>>(
                X, w1p, s1p, nullptr, nullptr, nullptr, T1);
            conv_mfma<32,32,16,1,8,16,1,1,1><<<2048, 256, 0, stream>>>(
                T1, w2p, s2p, X, nullptr, nullptr, T2);
        } else if (i == 12) {
            conv_mfma<32,64,16,2,8,8,0,1,1><<<1024, 256, 0, stream>>>(
                X, w1p, s1p, nullptr, nullptr, nullptr, T1);
            conv_mfma<64,64,8,1,8,8,2,32,16><<<1024, 256, 0, stream>>>(
                T1, w2p, s2p, X, rwT12, res_b12, T2);
        } else {
            conv_mfma<64,64,8,1,8,8,0,1,1><<<1024, 256, 0, stream>>>(
                X, w1p, s1p, nullptr, nullptr, nullptr, T1);
            conv_mfma<64,64,8,1,8,8,1,1,1><<<1024, 256, 0, stream>>>(
                T1, w2p, s2p, X, nullptr, nullptr, T2);
        }
        float* tmp = X; X = T2; T2 = tmp;
    }
    pool_fc<<<1024, 64, 0, stream>>>(X, fin_w, fin_b, outp);
}